// Round 17
// baseline (454.301 us; speedup 1.0000x reference)
//
#include <hip/hip_runtime.h>

// ROUND 17 — R16 with the nontemporal-store type fixed (f32x4 ext-vector, not
// HIP float4). scores: dbuf Q staging + nt stores; out_gemm: fused diag*v.

#define NB 4
#define NT 2048
#define NC 1024
#define NH 16
#define NHD 64
#define BH (NB * NH)            // 64
typedef unsigned short ushort_t;
#define SLAB ((size_t)NT * (size_t)NT)

typedef __attribute__((ext_vector_type(8))) short short8;   // 8 bf16 = 4 VGPR
typedef __attribute__((ext_vector_type(4))) float f32x4;

__device__ __forceinline__ ushort_t f2bf(float f) {
    unsigned int x = __float_as_uint(f);
    x += 0x7fffu + ((x >> 16) & 1u);   // RTNE; values finite
    return (ushort_t)(x >> 16);
}
__device__ __forceinline__ float bf2f(ushort_t u) {
    return __uint_as_float(((unsigned int)u) << 16);
}

#define GLD_LDS16(g, l) \
    __builtin_amdgcn_global_load_lds( \
        (const __attribute__((address_space(1))) unsigned int*)(g), \
        (__attribute__((address_space(3))) unsigned int*)(l), 16, 0, 0)

// ---- P1: x f32 -> xbf bf16 --------------------------------------------------
__global__ __launch_bounds__(256) void cvt_x(
    const float* __restrict__ x, ushort_t* __restrict__ xbf)
{
    const size_t o = ((size_t)blockIdx.x * 256 + threadIdx.x) * 4;
    float4 u = *(const float4*)(x + o);
    ushort4 v;
    v.x = f2bf(u.x); v.y = f2bf(u.y); v.z = f2bf(u.z); v.w = f2bf(u.w);
    *(ushort4*)(xbf + o) = v;
}

// ---- P2: W[sel][h][c][d] f32 -> Wt[n][c] bf16 (n = sel*1024+h*64+d) ---------
__global__ __launch_bounds__(256) void cvt_w(
    const float* __restrict__ Wq, const float* __restrict__ Wk,
    const float* __restrict__ Wv, ushort_t* __restrict__ Wt)
{
    const int o = blockIdx.x * 256 + threadIdx.x;    // < 3*16*64*1024
    const int sel = o >> 20;
    const int h = (o >> 16) & 15;
    const int idx = o & 65535;
    const int d = idx >> 10, c = idx & 1023;
    const float* W = (sel == 0 ? Wq : (sel == 1 ? Wk : Wv));
    Wt[o] = f2bf(W[(size_t)h * 65536 + (size_t)c * 64 + d]);
}

// ---- P3: Wp f32 [n][c] -> bf16 ----------------------------------------------
__global__ __launch_bounds__(256) void cvt_wp(
    const float* __restrict__ Wp, ushort_t* __restrict__ Wpb)
{
    const size_t o = ((size_t)blockIdx.x * 256 + threadIdx.x) * 4;
    float4 u = *(const float4*)(Wp + o);
    ushort4 v;
    v.x = f2bf(u.x); v.y = f2bf(u.y); v.z = f2bf(u.z); v.w = f2bf(u.w);
    *(ushort4*)(Wpb + o) = v;
}

// ---- K1: qkv GEMM (verified R14/R15) ----------------------------------------
__global__ __launch_bounds__(256) void qkv_gemm2(
    const ushort_t* __restrict__ xbf, const ushort_t* __restrict__ Wt,
    ushort_t* __restrict__ qo, ushort_t* __restrict__ ko, ushort_t* __restrict__ vo)
{
    __shared__ ushort_t smA[128 * 64];   // 16 KB
    __shared__ ushort_t smB[128 * 64];   // 16 KB
    const int n0 = blockIdx.x * 128;
    const int m0 = blockIdx.y * 128;
    const int tid = threadIdx.x;
    const int wid = tid >> 6, l = tid & 63, lr = l & 15, lg = l >> 4;
    const int wr = wid >> 1, wc = wid & 1;

    const int srow = wid * 32 + (l >> 3);            // + j*8
    const int scol0 = ((l & 7) ^ (srow & 7)) * 8;    // pre-swizzled elem offset

    f32x4 acc[4][4];
    #pragma unroll
    for (int i = 0; i < 4; ++i)
        #pragma unroll
        for (int j = 0; j < 4; ++j) acc[i][j] = (f32x4){0.f, 0.f, 0.f, 0.f};

    for (int k0 = 0; k0 < NC; k0 += 64) {
        #pragma unroll
        for (int j = 0; j < 4; ++j) {
            const int row = srow + j * 8;
            GLD_LDS16(xbf + (size_t)(m0 + row) * NC + k0 + scol0,
                      &smA[wid * 2048 + j * 512]);
            GLD_LDS16(Wt + (size_t)(n0 + row) * NC + k0 + scol0,
                      &smB[wid * 2048 + j * 512]);
        }
        __syncthreads();
        short8 a[4][2], b[4][2];
        #pragma unroll
        for (int mi = 0; mi < 4; ++mi) {
            const int rowA = 64 * wr + 16 * mi + lr;
            const int sw = (rowA & 7) * 8;
            a[mi][0] = *(const short8*)&smA[rowA * 64 + ((8 * lg) ^ sw)];
            a[mi][1] = *(const short8*)&smA[rowA * 64 + ((32 + 8 * lg) ^ sw)];
        }
        #pragma unroll
        for (int ni = 0; ni < 4; ++ni) {
            const int rowB = 64 * wc + 16 * ni + lr;
            const int sw = (rowB & 7) * 8;
            b[ni][0] = *(const short8*)&smB[rowB * 64 + ((8 * lg) ^ sw)];
            b[ni][1] = *(const short8*)&smB[rowB * 64 + ((32 + 8 * lg) ^ sw)];
        }
        #pragma unroll
        for (int mi = 0; mi < 4; ++mi)
            #pragma unroll
            for (int ni = 0; ni < 4; ++ni) {
                acc[mi][ni] = __builtin_amdgcn_mfma_f32_16x16x32_bf16(
                    a[mi][0], b[ni][0], acc[mi][ni], 0, 0, 0);
                acc[mi][ni] = __builtin_amdgcn_mfma_f32_16x16x32_bf16(
                    a[mi][1], b[ni][1], acc[mi][ni], 0, 0, 0);
            }
        __syncthreads();
    }
    const int selh = blockIdx.x * 2 + wc;
    const int sel = selh >> 4, h = selh & 15;
    ushort_t* outp = (sel == 0 ? qo : (sel == 1 ? ko : vo));
    #pragma unroll
    for (int mi = 0; mi < 4; ++mi) {
        #pragma unroll
        for (int r = 0; r < 4; ++r) {
            const int m = m0 + 64 * wr + 16 * mi + 4 * lg + r;
            const int bb = m >> 11, tt = m & 2047;
            ushort_t* orow = outp + ((size_t)(bb * NH + h) * NT + tt) * NHD;
            #pragma unroll
            for (int ni = 0; ni < 4; ++ni)
                orow[16 * ni + lr] = f2bf(acc[mi][ni][r]);
        }
    }
}

// ---- K2: scores, double-buffered Q, nontemporal w stores --------------------
__global__ __launch_bounds__(256) void scores_mfma(
    const ushort_t* __restrict__ q, const ushort_t* __restrict__ k,
    float* __restrict__ w, float* __restrict__ diag)
{
    __shared__ ushort_t smQ[2][64 * 64];    // 2 x 8 KB
    const int ib = blockIdx.x, bh = blockIdx.y;
    const int tid = threadIdx.x;
    const int wid = tid >> 6, l = tid & 63, lr = l & 15, lg = l >> 4;
    const int i0 = ib * 64;
    const ushort_t* kb = k + (size_t)bh * (NT * NHD);
    const ushort_t* qb = q + (size_t)bh * (NT * NHD);
    float* wbase = w + (size_t)bh * SLAB;

    short8 af0, af1;    // A = K rows, m = i_local
    {
        const ushort_t* kp = kb + (size_t)(i0 + wid * 16 + lr) * NHD + 8 * lg;
        af0 = *(const short8*)kp;
        af1 = *(const short8*)(kp + 32);
    }
    const int gi_base = i0 + wid * 16 + 4 * lg;     // + r

    const int srlo = l >> 3;                        // 0..7 (== staged row & 7)
    const int scol = ((l & 7) ^ srlo) * 8;          // pre-swizzled elem offset

    #define STAGEQ(buf, jt)                                                  \
        _Pragma("unroll")                                                    \
        for (int j = 0; j < 2; ++j) {                                        \
            const int row_ = wid * 16 + j * 8 + srlo;                        \
            GLD_LDS16(qb + (size_t)((jt) * 64 + row_) * NHD + scol,          \
                      &smQ[buf][(wid * 16 + j * 8) * 64]);                   \
        }

    // ---------------- PASS A: row sums ----------------
    float lsum[4] = {0.f, 0.f, 0.f, 0.f};
    STAGEQ(0, 0);
    __syncthreads();
    for (int jt = 0; jt <= ib; ++jt) {
        const int cur = jt & 1;
        if (jt < ib) { STAGEQ(cur ^ 1, jt + 1); }
        #pragma unroll
        for (int nt = 0; nt < 4; ++nt) {
            const int rowB = nt * 16 + lr;
            const int sw = (rowB & 7) * 8;
            const short8 b0 = *(const short8*)&smQ[cur][rowB * 64 + ((8 * lg) ^ sw)];
            const short8 b1 = *(const short8*)&smQ[cur][rowB * 64 + ((32 + 8 * lg) ^ sw)];
            f32x4 acc = {0,0,0,0};
            acc = __builtin_amdgcn_mfma_f32_16x16x32_bf16(af0, b0, acc, 0, 0, 0);
            acc = __builtin_amdgcn_mfma_f32_16x16x32_bf16(af1, b1, acc, 0, 0, 0);
            const int gj = jt * 64 + nt * 16 + lr;
            #pragma unroll
            for (int r = 0; r < 4; ++r) {
                float e = __expf(acc[r] * 0.03125f);
                lsum[r] += (gj <= gi_base + r) ? e : 0.f;
            }
        }
        __syncthreads();   // drains the prefetch issued above (T3 minimal recipe)
    }
    float linv[4];
    #pragma unroll
    for (int r = 0; r < 4; ++r) {
        float v = lsum[r];
        v += __shfl_xor(v, 1);
        v += __shfl_xor(v, 2);
        v += __shfl_xor(v, 4);
        v += __shfl_xor(v, 8);
        linv[r] = 1.0f / v;
    }
    // ---------------- PASS B: write normalized ----------------
    STAGEQ(0, 0);
    __syncthreads();
    for (int jt = 0; jt <= ib; ++jt) {
        const int cur = jt & 1;
        if (jt < ib) { STAGEQ(cur ^ 1, jt + 1); }
        #pragma unroll
        for (int nt = 0; nt < 4; ++nt) {
            const int rowB = nt * 16 + lr;
            const int sw = (rowB & 7) * 8;
            const short8 b0 = *(const short8*)&smQ[cur][rowB * 64 + ((8 * lg) ^ sw)];
            const short8 b1 = *(const short8*)&smQ[cur][rowB * 64 + ((32 + 8 * lg) ^ sw)];
            f32x4 acc = {0,0,0,0};
            acc = __builtin_amdgcn_mfma_f32_16x16x32_bf16(af0, b0, acc, 0, 0, 0);
            acc = __builtin_amdgcn_mfma_f32_16x16x32_bf16(af1, b1, acc, 0, 0, 0);
            const int gj = jt * 64 + nt * 16 + lr;
            #pragma unroll
            for (int r = 0; r < 4; ++r) {
                const int gi = gi_base + r;
                float e = __expf(acc[r] * 0.03125f) * linv[r];
                e = (gj <= gi) ? e : 0.f;
                __builtin_nontemporal_store(e, &wbase[(size_t)gi * NT + gj]);
                if (gj == gi) diag[(size_t)bh * NT + gi] = e;
            }
        }
        __syncthreads();
    }
    #undef STAGEQ
    // zero-fill above the diagonal block (nontemporal, f32x4 ext-vector)
    const f32x4 z4 = {0.f, 0.f, 0.f, 0.f};
    for (int jt = ib + 1; jt < NT / 64; ++jt) {
        #pragma unroll
        for (int it = 0; it < 4; ++it) {
            const int row = i0 + wid * 16 + it * 4 + lg;
            f32x4* p = (f32x4*)&wbase[(size_t)row * NT + jt * 64 + lr * 4];
            __builtin_nontemporal_store(z4, p);
        }
    }
}

// ---- K3: out = (diag*v concat) @ Wp^T + bp; A reg-staged with fused scale ---
__global__ __launch_bounds__(256) void out_gemm(
    const ushort_t* __restrict__ vs, const float* __restrict__ diag,
    const ushort_t* __restrict__ Wpb, const float* __restrict__ bpv,
    float* __restrict__ out)
{
    __shared__ ushort_t smA[128 * 64];   // 16 KB
    __shared__ ushort_t smB[128 * 64];   // 16 KB
    const int n0 = blockIdx.x * 128;
    const int m0 = blockIdx.y * 128;
    const int tid = threadIdx.x;
    const int wid = tid >> 6, l = tid & 63, lr = l & 15, lg = l >> 4;
    const int wr = wid >> 1, wc = wid & 1;

    const int srow = wid * 32 + (l >> 3);            // + j*8; srow&7 == l>>3
    const int scol0 = ((l & 7) ^ (srow & 7)) * 8;    // swizzled col (elems)

    f32x4 acc[4][4];
    #pragma unroll
    for (int i = 0; i < 4; ++i)
        #pragma unroll
        for (int j = 0; j < 4; ++j) acc[i][j] = (f32x4){0.f, 0.f, 0.f, 0.f};

    for (int k0 = 0; k0 < NC; k0 += 64) {
        const int h = k0 >> 6;
        // B: async gload_lds, pre-swizzled source (verified pattern)
        #pragma unroll
        for (int j = 0; j < 4; ++j) {
            GLD_LDS16(Wpb + (size_t)(n0 + srow + j * 8) * NC + k0 + scol0,
                      &smB[wid * 2048 + j * 512]);
        }
        // A: reg-staged, diag*v fused, ds_write at the same swizzled offset
        #pragma unroll
        for (int j = 0; j < 4; ++j) {
            const int row = srow + j * 8;
            const int m = m0 + row, bb = m >> 11, tt = m & 2047;
            const size_t bhT = (size_t)(bb * NH + h) * NT + tt;
            const short8 u = *(const short8*)(vs + bhT * NHD + (l & 7) * 8);
            const float dg = diag[bhT];
            short8 sc;
            #pragma unroll
            for (int e = 0; e < 8; ++e)
                sc[e] = (short)f2bf(bf2f((ushort_t)u[e]) * dg);
            *(short8*)&smA[row * 64 + scol0] = sc;
        }
        __syncthreads();
        short8 a[4][2], b[4][2];
        #pragma unroll
        for (int mi = 0; mi < 4; ++mi) {
            const int rowA = 64 * wr + 16 * mi + lr;
            const int sw = (rowA & 7) * 8;
            a[mi][0] = *(const short8*)&smA[rowA * 64 + ((8 * lg) ^ sw)];
            a[mi][1] = *(const short8*)&smA[rowA * 64 + ((32 + 8 * lg) ^ sw)];
        }
        #pragma unroll
        for (int ni = 0; ni < 4; ++ni) {
            const int rowB = 64 * wc + 16 * ni + lr;
            const int sw = (rowB & 7) * 8;
            b[ni][0] = *(const short8*)&smB[rowB * 64 + ((8 * lg) ^ sw)];
            b[ni][1] = *(const short8*)&smB[rowB * 64 + ((32 + 8 * lg) ^ sw)];
        }
        #pragma unroll
        for (int mi = 0; mi < 4; ++mi)
            #pragma unroll
            for (int ni = 0; ni < 4; ++ni) {
                acc[mi][ni] = __builtin_amdgcn_mfma_f32_16x16x32_bf16(
                    a[mi][0], b[ni][0], acc[mi][ni], 0, 0, 0);
                acc[mi][ni] = __builtin_amdgcn_mfma_f32_16x16x32_bf16(
                    a[mi][1], b[ni][1], acc[mi][ni], 0, 0, 0);
            }
        __syncthreads();
    }
    float bias[4];
    #pragma unroll
    for (int ni = 0; ni < 4; ++ni) bias[ni] = bpv[n0 + 64 * wc + 16 * ni + lr];
    #pragma unroll
    for (int mi = 0; mi < 4; ++mi) {
        #pragma unroll
        for (int r = 0; r < 4; ++r) {
            const int m = m0 + 64 * wr + 16 * mi + 4 * lg + r;
            float* orow = out + (size_t)m * NC + n0 + 64 * wc;
            #pragma unroll
            for (int ni = 0; ni < 4; ++ni)
                __builtin_nontemporal_store(acc[mi][ni][r] + bias[ni],
                                            &orow[16 * ni + lr]);
        }
    }
}

extern "C" void kernel_launch(void* const* d_in, const int* in_sizes, int n_in,
                              void* d_out, int out_size, void* d_ws, size_t ws_size,
                              hipStream_t stream)
{
    const float* x  = (const float*)d_in[0];
    const float* Wq = (const float*)d_in[1];
    const float* Wk = (const float*)d_in[2];
    const float* Wv = (const float*)d_in[3];
    const float* Wp = (const float*)d_in[4];
    const float* bp = (const float*)d_in[5];

    float* out = (float*)d_out;                      // f32 outputs
    float* w = out + (size_t)NB * NT * NC;           // weights region (f32)

    ushort_t* xbf = (ushort_t*)d_ws;                             // 16.8 MB
    ushort_t* Wt  = xbf + (size_t)NB * NT * NC;                  // 6.3 MB
    ushort_t* qs  = Wt + (size_t)3 * NH * NHD * NC;              // 3 x 16.8 MB
    ushort_t* ks  = qs + (size_t)BH * NT * NHD;
    ushort_t* vs  = ks + (size_t)BH * NT * NHD;
    float* diag   = (float*)(vs + (size_t)BH * NT * NHD);        // 0.5 MB
    ushort_t* Wpb = (ushort_t*)(diag + (size_t)BH * NT);         // 2 MB

    cvt_x<<<(NB * NT * NC) / 1024, 256, 0, stream>>>(x, xbf);
    cvt_w<<<(3 * NH * NHD * NC) / 256, 256, 0, stream>>>(Wq, Wk, Wv, Wt);
    cvt_wp<<<(NC * NC) / 1024, 256, 0, stream>>>(Wp, Wpb);
    qkv_gemm2<<<dim3(24, 64), 256, 0, stream>>>(xbf, Wt, qs, ks, vs);
    scores_mfma<<<dim3(NT / 64, BH), 256, 0, stream>>>(qs, ks, w, diag);
    out_gemm<<<dim3(8, 64), 256, 0, stream>>>(vs, diag, Wpb, bp, out);
}

// Round 18
// 391.723 us; speedup vs baseline: 1.1598x; 1.1598x over previous
//
#include <hip/hip_runtime.h>

// ROUND 18 — scores pass-B stores coalesced via LDS transpose (f32x4, 256B
// segments); 3 cvt kernels merged into 1; qkv grid XCD-swizzled (T1).

#define NB 4
#define NT 2048
#define NC 1024
#define NH 16
#define NHD 64
#define BH (NB * NH)            // 64
typedef unsigned short ushort_t;
#define SLAB ((size_t)NT * (size_t)NT)

typedef __attribute__((ext_vector_type(8))) short short8;   // 8 bf16 = 4 VGPR
typedef __attribute__((ext_vector_type(4))) float f32x4;

__device__ __forceinline__ ushort_t f2bf(float f) {
    unsigned int x = __float_as_uint(f);
    x += 0x7fffu + ((x >> 16) & 1u);   // RTNE; values finite
    return (ushort_t)(x >> 16);
}
__device__ __forceinline__ float bf2f(ushort_t u) {
    return __uint_as_float(((unsigned int)u) << 16);
}

#define GLD_LDS16(g, l) \
    __builtin_amdgcn_global_load_lds( \
        (const __attribute__((address_space(1))) unsigned int*)(g), \
        (__attribute__((address_space(3))) unsigned int*)(l), 16, 0, 0)

// ---- P: all f32->bf16 conversions in one kernel -----------------------------
// blocks [0,8192): x (4 elem/thread, contiguous)
// blocks [8192,9216): Wp (4 elem/thread, contiguous)
// blocks [9216,21504): W gather-transpose (1 elem/thread)
__global__ __launch_bounds__(256) void cvt_all(
    const float* __restrict__ x, const float* __restrict__ Wq,
    const float* __restrict__ Wk, const float* __restrict__ Wv,
    const float* __restrict__ Wp,
    ushort_t* __restrict__ xbf, ushort_t* __restrict__ Wpb,
    ushort_t* __restrict__ Wt)
{
    const int b = blockIdx.x;
    if (b < 8192 + 1024) {
        const float* src = (b < 8192) ? x : Wp;
        ushort_t* dst = (b < 8192) ? xbf : Wpb;
        const size_t o = ((size_t)(b < 8192 ? b : b - 8192) * 256 + threadIdx.x) * 4;
        float4 u = *(const float4*)(src + o);
        ushort4 v;
        v.x = f2bf(u.x); v.y = f2bf(u.y); v.z = f2bf(u.z); v.w = f2bf(u.w);
        *(ushort4*)(dst + o) = v;
    } else {
        const int o = (b - 9216) * 256 + threadIdx.x;   // < 3*16*64*1024
        const int sel = o >> 20;
        const int h = (o >> 16) & 15;
        const int idx = o & 65535;
        const int d = idx >> 10, c = idx & 1023;
        const float* W = (sel == 0 ? Wq : (sel == 1 ? Wk : Wv));
        Wt[o] = f2bf(W[(size_t)h * 65536 + (size_t)c * 64 + d]);
    }
}

// ---- K1: qkv GEMM (verified R14/R15), 1-D grid + XCD swizzle ----------------
__global__ __launch_bounds__(256) void qkv_gemm2(
    const ushort_t* __restrict__ xbf, const ushort_t* __restrict__ Wt,
    ushort_t* __restrict__ qo, ushort_t* __restrict__ ko, ushort_t* __restrict__ vo)
{
    __shared__ ushort_t smA[128 * 64];   // 16 KB
    __shared__ ushort_t smB[128 * 64];   // 16 KB
    // T1: 1536 blocks, 1536 % 8 == 0 -> swz = (bid%8)*192 + bid/8
    const int bid = blockIdx.x;
    const int swz = (bid & 7) * 192 + (bid >> 3);
    const int n0 = (swz % 24) * 128;
    const int m0 = (swz / 24) * 128;
    const int tid = threadIdx.x;
    const int wid = tid >> 6, l = tid & 63, lr = l & 15, lg = l >> 4;
    const int wr = wid >> 1, wc = wid & 1;

    const int srow = wid * 32 + (l >> 3);            // + j*8
    const int scol0 = ((l & 7) ^ (srow & 7)) * 8;    // pre-swizzled elem offset

    f32x4 acc[4][4];
    #pragma unroll
    for (int i = 0; i < 4; ++i)
        #pragma unroll
        for (int j = 0; j < 4; ++j) acc[i][j] = (f32x4){0.f, 0.f, 0.f, 0.f};

    for (int k0 = 0; k0 < NC; k0 += 64) {
        #pragma unroll
        for (int j = 0; j < 4; ++j) {
            const int row = srow + j * 8;
            GLD_LDS16(xbf + (size_t)(m0 + row) * NC + k0 + scol0,
                      &smA[wid * 2048 + j * 512]);
            GLD_LDS16(Wt + (size_t)(n0 + row) * NC + k0 + scol0,
                      &smB[wid * 2048 + j * 512]);
        }
        __syncthreads();
        short8 a[4][2], b[4][2];
        #pragma unroll
        for (int mi = 0; mi < 4; ++mi) {
            const int rowA = 64 * wr + 16 * mi + lr;
            const int sw = (rowA & 7) * 8;
            a[mi][0] = *(const short8*)&smA[rowA * 64 + ((8 * lg) ^ sw)];
            a[mi][1] = *(const short8*)&smA[rowA * 64 + ((32 + 8 * lg) ^ sw)];
        }
        #pragma unroll
        for (int ni = 0; ni < 4; ++ni) {
            const int rowB = 64 * wc + 16 * ni + lr;
            const int sw = (rowB & 7) * 8;
            b[ni][0] = *(const short8*)&smB[rowB * 64 + ((8 * lg) ^ sw)];
            b[ni][1] = *(const short8*)&smB[rowB * 64 + ((32 + 8 * lg) ^ sw)];
        }
        #pragma unroll
        for (int mi = 0; mi < 4; ++mi)
            #pragma unroll
            for (int ni = 0; ni < 4; ++ni) {
                acc[mi][ni] = __builtin_amdgcn_mfma_f32_16x16x32_bf16(
                    a[mi][0], b[ni][0], acc[mi][ni], 0, 0, 0);
                acc[mi][ni] = __builtin_amdgcn_mfma_f32_16x16x32_bf16(
                    a[mi][1], b[ni][1], acc[mi][ni], 0, 0, 0);
            }
        __syncthreads();
    }
    const int selh = (n0 >> 6) + wc;
    const int sel = selh >> 4, h = selh & 15;
    ushort_t* outp = (sel == 0 ? qo : (sel == 1 ? ko : vo));
    #pragma unroll
    for (int mi = 0; mi < 4; ++mi) {
        #pragma unroll
        for (int r = 0; r < 4; ++r) {
            const int m = m0 + 64 * wr + 16 * mi + 4 * lg + r;
            const int bb = m >> 11, tt = m & 2047;
            ushort_t* orow = outp + ((size_t)(bb * NH + h) * NT + tt) * NHD;
            #pragma unroll
            for (int ni = 0; ni < 4; ++ni)
                orow[16 * ni + lr] = f2bf(acc[mi][ni][r]);
        }
    }
}

// ---- K2: scores; pass B stores via LDS-transpose (coalesced f32x4) ----------
__global__ __launch_bounds__(256) void scores_mfma(
    const ushort_t* __restrict__ q, const ushort_t* __restrict__ k,
    float* __restrict__ w, float* __restrict__ diag)
{
    __shared__ ushort_t smQ[2][64 * 64];    // 2 x 8 KB
    __shared__ float eT[64][68];            // 17 KB, padded (2-way max)
    const int ib = blockIdx.x, bh = blockIdx.y;
    const int tid = threadIdx.x;
    const int wid = tid >> 6, l = tid & 63, lr = l & 15, lg = l >> 4;
    const int i0 = ib * 64;
    const ushort_t* kb = k + (size_t)bh * (NT * NHD);
    const ushort_t* qb = q + (size_t)bh * (NT * NHD);
    float* wbase = w + (size_t)bh * SLAB;

    short8 af0, af1;    // A = K rows, m = i_local
    {
        const ushort_t* kp = kb + (size_t)(i0 + wid * 16 + lr) * NHD + 8 * lg;
        af0 = *(const short8*)kp;
        af1 = *(const short8*)(kp + 32);
    }
    const int gi_base = i0 + wid * 16 + 4 * lg;     // + r

    const int srlo = l >> 3;                        // 0..7 (== staged row & 7)
    const int scol = ((l & 7) ^ srlo) * 8;          // pre-swizzled elem offset

    #define STAGEQ(buf, jt)                                                  \
        _Pragma("unroll")                                                    \
        for (int j = 0; j < 2; ++j) {                                        \
            const int row_ = wid * 16 + j * 8 + srlo;                        \
            GLD_LDS16(qb + (size_t)((jt) * 64 + row_) * NHD + scol,          \
                      &smQ[buf][(wid * 16 + j * 8) * 64]);                   \
        }

    // ---------------- PASS A: row sums ----------------
    float lsum[4] = {0.f, 0.f, 0.f, 0.f};
    STAGEQ(0, 0);
    __syncthreads();
    for (int jt = 0; jt <= ib; ++jt) {
        const int cur = jt & 1;
        if (jt < ib) { STAGEQ(cur ^ 1, jt + 1); }
        #pragma unroll
        for (int nt = 0; nt < 4; ++nt) {
            const int rowB = nt * 16 + lr;
            const int sw = (rowB & 7) * 8;
            const short8 b0 = *(const short8*)&smQ[cur][rowB * 64 + ((8 * lg) ^ sw)];
            const short8 b1 = *(const short8*)&smQ[cur][rowB * 64 + ((32 + 8 * lg) ^ sw)];
            f32x4 acc = {0,0,0,0};
            acc = __builtin_amdgcn_mfma_f32_16x16x32_bf16(af0, b0, acc, 0, 0, 0);
            acc = __builtin_amdgcn_mfma_f32_16x16x32_bf16(af1, b1, acc, 0, 0, 0);
            const int gj = jt * 64 + nt * 16 + lr;
            #pragma unroll
            for (int r = 0; r < 4; ++r) {
                float e = __expf(acc[r] * 0.03125f);
                lsum[r] += (gj <= gi_base + r) ? e : 0.f;
            }
        }
        __syncthreads();
    }
    float linv[4];
    #pragma unroll
    for (int r = 0; r < 4; ++r) {
        float v = lsum[r];
        v += __shfl_xor(v, 1);
        v += __shfl_xor(v, 2);
        v += __shfl_xor(v, 4);
        v += __shfl_xor(v, 8);
        linv[r] = 1.0f / v;
    }
    // ---------------- PASS B: normalized writes via LDS transpose ------------
    STAGEQ(0, 0);
    __syncthreads();
    for (int jt = 0; jt <= ib; ++jt) {
        const int cur = jt & 1;
        if (jt < ib) { STAGEQ(cur ^ 1, jt + 1); }
        #pragma unroll
        for (int nt = 0; nt < 4; ++nt) {
            const int rowB = nt * 16 + lr;
            const int sw = (rowB & 7) * 8;
            const short8 b0 = *(const short8*)&smQ[cur][rowB * 64 + ((8 * lg) ^ sw)];
            const short8 b1 = *(const short8*)&smQ[cur][rowB * 64 + ((32 + 8 * lg) ^ sw)];
            f32x4 acc = {0,0,0,0};
            acc = __builtin_amdgcn_mfma_f32_16x16x32_bf16(af0, b0, acc, 0, 0, 0);
            acc = __builtin_amdgcn_mfma_f32_16x16x32_bf16(af1, b1, acc, 0, 0, 0);
            const int gj = jt * 64 + nt * 16 + lr;
            #pragma unroll
            for (int r = 0; r < 4; ++r) {
                const int gi = gi_base + r;
                float e = __expf(acc[r] * 0.03125f) * linv[r];
                e = (gj <= gi) ? e : 0.f;
                eT[wid * 16 + 4 * lg + r][nt * 16 + lr] = e;
                if (gj == gi) diag[(size_t)bh * NT + gi] = e;
            }
        }
        __syncthreads();   // eT complete; prefetch drained
        #pragma unroll
        for (int it = 0; it < 4; ++it) {
            const int chunk = it * 256 + tid;
            const int row = chunk >> 4, c4 = chunk & 15;
            const f32x4 v4 = *(const f32x4*)&eT[row][c4 * 4];
            __builtin_nontemporal_store(
                v4, (f32x4*)&wbase[(size_t)(i0 + row) * NT + jt * 64 + c4 * 4]);
        }
        __syncthreads();   // eT consumed before next tile overwrites
    }
    #undef STAGEQ
    // zero-fill above the diagonal block (nontemporal f32x4)
    const f32x4 z4 = {0.f, 0.f, 0.f, 0.f};
    for (int jt = ib + 1; jt < NT / 64; ++jt) {
        #pragma unroll
        for (int it = 0; it < 4; ++it) {
            const int row = i0 + wid * 16 + it * 4 + lg;
            f32x4* p = (f32x4*)&wbase[(size_t)row * NT + jt * 64 + lr * 4];
            __builtin_nontemporal_store(z4, p);
        }
    }
}

// ---- K3: out = (diag*v concat) @ Wp^T + bp; A reg-staged fused scale --------
__global__ __launch_bounds__(256) void out_gemm(
    const ushort_t* __restrict__ vs, const float* __restrict__ diag,
    const ushort_t* __restrict__ Wpb, const float* __restrict__ bpv,
    float* __restrict__ out)
{
    __shared__ ushort_t smA[128 * 64];   // 16 KB
    __shared__ ushort_t smB[128 * 64];   // 16 KB
    const int n0 = blockIdx.x * 128;
    const int m0 = blockIdx.y * 128;
    const int tid = threadIdx.x;
    const int wid = tid >> 6, l = tid & 63, lr = l & 15, lg = l >> 4;
    const int wr = wid >> 1, wc = wid & 1;

    const int srow = wid * 32 + (l >> 3);            // + j*8; srow&7 == l>>3
    const int scol0 = ((l & 7) ^ (srow & 7)) * 8;    // swizzled col (elems)

    f32x4 acc[4][4];
    #pragma unroll
    for (int i = 0; i < 4; ++i)
        #pragma unroll
        for (int j = 0; j < 4; ++j) acc[i][j] = (f32x4){0.f, 0.f, 0.f, 0.f};

    for (int k0 = 0; k0 < NC; k0 += 64) {
        const int h = k0 >> 6;
        #pragma unroll
        for (int j = 0; j < 4; ++j) {
            GLD_LDS16(Wpb + (size_t)(n0 + srow + j * 8) * NC + k0 + scol0,
                      &smB[wid * 2048 + j * 512]);
        }
        #pragma unroll
        for (int j = 0; j < 4; ++j) {
            const int row = srow + j * 8;
            const int m = m0 + row, bb = m >> 11, tt = m & 2047;
            const size_t bhT = (size_t)(bb * NH + h) * NT + tt;
            const short8 u = *(const short8*)(vs + bhT * NHD + (l & 7) * 8);
            const float dg = diag[bhT];
            short8 sc;
            #pragma unroll
            for (int e = 0; e < 8; ++e)
                sc[e] = (short)f2bf(bf2f((ushort_t)u[e]) * dg);
            *(short8*)&smA[row * 64 + scol0] = sc;
        }
        __syncthreads();
        short8 a[4][2], b[4][2];
        #pragma unroll
        for (int mi = 0; mi < 4; ++mi) {
            const int rowA = 64 * wr + 16 * mi + lr;
            const int sw = (rowA & 7) * 8;
            a[mi][0] = *(const short8*)&smA[rowA * 64 + ((8 * lg) ^ sw)];
            a[mi][1] = *(const short8*)&smA[rowA * 64 + ((32 + 8 * lg) ^ sw)];
        }
        #pragma unroll
        for (int ni = 0; ni < 4; ++ni) {
            const int rowB = 64 * wc + 16 * ni + lr;
            const int sw = (rowB & 7) * 8;
            b[ni][0] = *(const short8*)&smB[rowB * 64 + ((8 * lg) ^ sw)];
            b[ni][1] = *(const short8*)&smB[rowB * 64 + ((32 + 8 * lg) ^ sw)];
        }
        #pragma unroll
        for (int mi = 0; mi < 4; ++mi)
            #pragma unroll
            for (int ni = 0; ni < 4; ++ni) {
                acc[mi][ni] = __builtin_amdgcn_mfma_f32_16x16x32_bf16(
                    a[mi][0], b[ni][0], acc[mi][ni], 0, 0, 0);
                acc[mi][ni] = __builtin_amdgcn_mfma_f32_16x16x32_bf16(
                    a[mi][1], b[ni][1], acc[mi][ni], 0, 0, 0);
            }
        __syncthreads();
    }
    float bias[4];
    #pragma unroll
    for (int ni = 0; ni < 4; ++ni) bias[ni] = bpv[n0 + 64 * wc + 16 * ni + lr];
    #pragma unroll
    for (int mi = 0; mi < 4; ++mi) {
        #pragma unroll
        for (int r = 0; r < 4; ++r) {
            const int m = m0 + 64 * wr + 16 * mi + 4 * lg + r;
            float* orow = out + (size_t)m * NC + n0 + 64 * wc;
            #pragma unroll
            for (int ni = 0; ni < 4; ++ni)
                __builtin_nontemporal_store(acc[mi][ni][r] + bias[ni],
                                            &orow[16 * ni + lr]);
        }
    }
}

extern "C" void kernel_launch(void* const* d_in, const int* in_sizes, int n_in,
                              void* d_out, int out_size, void* d_ws, size_t ws_size,
                              hipStream_t stream)
{
    const float* x  = (const float*)d_in[0];
    const float* Wq = (const float*)d_in[1];
    const float* Wk = (const float*)d_in[2];
    const float* Wv = (const float*)d_in[3];
    const float* Wp = (const float*)d_in[4];
    const float* bp = (const float*)d_in[5];

    float* out = (float*)d_out;                      // f32 outputs
    float* w = out + (size_t)NB * NT * NC;           // weights region (f32)

    ushort_t* xbf = (ushort_t*)d_ws;                             // 16.8 MB
    ushort_t* Wt  = xbf + (size_t)NB * NT * NC;                  // 6.3 MB
    ushort_t* qs  = Wt + (size_t)3 * NH * NHD * NC;              // 3 x 16.8 MB
    ushort_t* ks  = qs + (size_t)BH * NT * NHD;
    ushort_t* vs  = ks + (size_t)BH * NT * NHD;
    float* diag   = (float*)(vs + (size_t)BH * NT * NHD);        // 0.5 MB
    ushort_t* Wpb = (ushort_t*)(diag + (size_t)BH * NT);         // 2 MB

    cvt_all<<<21504, 256, 0, stream>>>(x, Wq, Wk, Wv, Wp, xbf, Wpb, Wt);
    qkv_gemm2<<<1536, 256, 0, stream>>>(xbf, Wt, qs, ks, vs);
    scores_mfma<<<dim3(NT / 64, BH), 256, 0, stream>>>(qs, ks, w, diag);
    out_gemm<<<dim3(8, 64), 256, 0, stream>>>(vs, diag, Wpb, bp, out);
}

// Round 19
// 390.821 us; speedup vs baseline: 1.1624x; 1.0023x over previous
//
#include <hip/hip_runtime.h>

// ROUND 19 — scores: single-buffer smQ (25 KB LDS -> 6 blocks/CU), causal-mask
// loop specialization (masked work only at jt==ib), per-row 1KB zero-fill
// bursts. qkv/out/cvt unchanged (verified R14-R18).

#define NB 4
#define NT 2048
#define NC 1024
#define NH 16
#define NHD 64
#define BH (NB * NH)            // 64
typedef unsigned short ushort_t;
#define SLAB ((size_t)NT * (size_t)NT)

typedef __attribute__((ext_vector_type(8))) short short8;   // 8 bf16 = 4 VGPR
typedef __attribute__((ext_vector_type(4))) float f32x4;

__device__ __forceinline__ ushort_t f2bf(float f) {
    unsigned int x = __float_as_uint(f);
    x += 0x7fffu + ((x >> 16) & 1u);   // RTNE; values finite
    return (ushort_t)(x >> 16);
}
__device__ __forceinline__ float bf2f(ushort_t u) {
    return __uint_as_float(((unsigned int)u) << 16);
}

#define GLD_LDS16(g, l) \
    __builtin_amdgcn_global_load_lds( \
        (const __attribute__((address_space(1))) unsigned int*)(g), \
        (__attribute__((address_space(3))) unsigned int*)(l), 16, 0, 0)

// ---- P: all f32->bf16 conversions in one kernel -----------------------------
__global__ __launch_bounds__(256) void cvt_all(
    const float* __restrict__ x, const float* __restrict__ Wq,
    const float* __restrict__ Wk, const float* __restrict__ Wv,
    const float* __restrict__ Wp,
    ushort_t* __restrict__ xbf, ushort_t* __restrict__ Wpb,
    ushort_t* __restrict__ Wt)
{
    const int b = blockIdx.x;
    if (b < 8192 + 1024) {
        const float* src = (b < 8192) ? x : Wp;
        ushort_t* dst = (b < 8192) ? xbf : Wpb;
        const size_t o = ((size_t)(b < 8192 ? b : b - 8192) * 256 + threadIdx.x) * 4;
        float4 u = *(const float4*)(src + o);
        ushort4 v;
        v.x = f2bf(u.x); v.y = f2bf(u.y); v.z = f2bf(u.z); v.w = f2bf(u.w);
        *(ushort4*)(dst + o) = v;
    } else {
        const int o = (b - 9216) * 256 + threadIdx.x;   // < 3*16*64*1024
        const int sel = o >> 20;
        const int h = (o >> 16) & 15;
        const int idx = o & 65535;
        const int d = idx >> 10, c = idx & 1023;
        const float* W = (sel == 0 ? Wq : (sel == 1 ? Wk : Wv));
        Wt[o] = f2bf(W[(size_t)h * 65536 + (size_t)c * 64 + d]);
    }
}

// ---- K1: qkv GEMM (verified R14/R15), 1-D grid + XCD swizzle ----------------
__global__ __launch_bounds__(256) void qkv_gemm2(
    const ushort_t* __restrict__ xbf, const ushort_t* __restrict__ Wt,
    ushort_t* __restrict__ qo, ushort_t* __restrict__ ko, ushort_t* __restrict__ vo)
{
    __shared__ ushort_t smA[128 * 64];   // 16 KB
    __shared__ ushort_t smB[128 * 64];   // 16 KB
    const int bid = blockIdx.x;
    const int swz = (bid & 7) * 192 + (bid >> 3);
    const int n0 = (swz % 24) * 128;
    const int m0 = (swz / 24) * 128;
    const int tid = threadIdx.x;
    const int wid = tid >> 6, l = tid & 63, lr = l & 15, lg = l >> 4;
    const int wr = wid >> 1, wc = wid & 1;

    const int srow = wid * 32 + (l >> 3);            // + j*8
    const int scol0 = ((l & 7) ^ (srow & 7)) * 8;    // pre-swizzled elem offset

    f32x4 acc[4][4];
    #pragma unroll
    for (int i = 0; i < 4; ++i)
        #pragma unroll
        for (int j = 0; j < 4; ++j) acc[i][j] = (f32x4){0.f, 0.f, 0.f, 0.f};

    for (int k0 = 0; k0 < NC; k0 += 64) {
        #pragma unroll
        for (int j = 0; j < 4; ++j) {
            const int row = srow + j * 8;
            GLD_LDS16(xbf + (size_t)(m0 + row) * NC + k0 + scol0,
                      &smA[wid * 2048 + j * 512]);
            GLD_LDS16(Wt + (size_t)(n0 + row) * NC + k0 + scol0,
                      &smB[wid * 2048 + j * 512]);
        }
        __syncthreads();
        short8 a[4][2], b[4][2];
        #pragma unroll
        for (int mi = 0; mi < 4; ++mi) {
            const int rowA = 64 * wr + 16 * mi + lr;
            const int sw = (rowA & 7) * 8;
            a[mi][0] = *(const short8*)&smA[rowA * 64 + ((8 * lg) ^ sw)];
            a[mi][1] = *(const short8*)&smA[rowA * 64 + ((32 + 8 * lg) ^ sw)];
        }
        #pragma unroll
        for (int ni = 0; ni < 4; ++ni) {
            const int rowB = 64 * wc + 16 * ni + lr;
            const int sw = (rowB & 7) * 8;
            b[ni][0] = *(const short8*)&smB[rowB * 64 + ((8 * lg) ^ sw)];
            b[ni][1] = *(const short8*)&smB[rowB * 64 + ((32 + 8 * lg) ^ sw)];
        }
        #pragma unroll
        for (int mi = 0; mi < 4; ++mi)
            #pragma unroll
            for (int ni = 0; ni < 4; ++ni) {
                acc[mi][ni] = __builtin_amdgcn_mfma_f32_16x16x32_bf16(
                    a[mi][0], b[ni][0], acc[mi][ni], 0, 0, 0);
                acc[mi][ni] = __builtin_amdgcn_mfma_f32_16x16x32_bf16(
                    a[mi][1], b[ni][1], acc[mi][ni], 0, 0, 0);
            }
        __syncthreads();
    }
    const int selh = (n0 >> 6) + wc;
    const int sel = selh >> 4, h = selh & 15;
    ushort_t* outp = (sel == 0 ? qo : (sel == 1 ? ko : vo));
    #pragma unroll
    for (int mi = 0; mi < 4; ++mi) {
        #pragma unroll
        for (int r = 0; r < 4; ++r) {
            const int m = m0 + 64 * wr + 16 * mi + 4 * lg + r;
            const int bb = m >> 11, tt = m & 2047;
            ushort_t* orow = outp + ((size_t)(bb * NH + h) * NT + tt) * NHD;
            #pragma unroll
            for (int ni = 0; ni < 4; ++ni)
                orow[16 * ni + lr] = f2bf(acc[mi][ni][r]);
        }
    }
}

// ---- K2: scores; single-buffer smQ, mask-specialized loops ------------------
__global__ __launch_bounds__(256) void scores_mfma(
    const ushort_t* __restrict__ q, const ushort_t* __restrict__ k,
    float* __restrict__ w, float* __restrict__ diag)
{
    __shared__ ushort_t smQ[64 * 64];       // 8 KB
    __shared__ float eT[64][68];            // 17.4 KB
    const int ib = blockIdx.x, bh = blockIdx.y;
    const int tid = threadIdx.x;
    const int wid = tid >> 6, l = tid & 63, lr = l & 15, lg = l >> 4;
    const int i0 = ib * 64;
    const ushort_t* kb = k + (size_t)bh * (NT * NHD);
    const ushort_t* qb = q + (size_t)bh * (NT * NHD);
    float* wbase = w + (size_t)bh * SLAB;

    short8 af0, af1;    // A = K rows, m = i_local
    {
        const ushort_t* kp = kb + (size_t)(i0 + wid * 16 + lr) * NHD + 8 * lg;
        af0 = *(const short8*)kp;
        af1 = *(const short8*)(kp + 32);
    }
    const int gi_base = i0 + wid * 16 + 4 * lg;     // + r

    const int srlo = l >> 3;                        // 0..7 (== staged row & 7)
    const int scol = ((l & 7) ^ srlo) * 8;          // pre-swizzled elem offset

    #define STAGEQ(jt)                                                       \
        _Pragma("unroll")                                                    \
        for (int j = 0; j < 2; ++j) {                                        \
            const int row_ = wid * 16 + j * 8 + srlo;                        \
            GLD_LDS16(qb + (size_t)((jt) * 64 + row_) * NHD + scol,          \
                      &smQ[(wid * 16 + j * 8) * 64]);                        \
        }

    #define QK_TILE(acc, nt)                                                 \
        f32x4 acc = {0, 0, 0, 0};                                            \
        {                                                                    \
            const int rowB = (nt) * 16 + lr;                                 \
            const int sw = (rowB & 7) * 8;                                   \
            const short8 b0 = *(const short8*)&smQ[rowB * 64 + ((8 * lg) ^ sw)];          \
            const short8 b1 = *(const short8*)&smQ[rowB * 64 + ((32 + 8 * lg) ^ sw)];     \
            acc = __builtin_amdgcn_mfma_f32_16x16x32_bf16(af0, b0, acc, 0, 0, 0);         \
            acc = __builtin_amdgcn_mfma_f32_16x16x32_bf16(af1, b1, acc, 0, 0, 0);         \
        }

    // ---------------- PASS A: row sums ----------------
    float lsum[4] = {0.f, 0.f, 0.f, 0.f};
    for (int jt = 0; jt < ib; ++jt) {              // fully-unmasked tiles
        STAGEQ(jt);
        __syncthreads();
        #pragma unroll
        for (int nt = 0; nt < 4; ++nt) {
            QK_TILE(acc, nt);
            #pragma unroll
            for (int r = 0; r < 4; ++r)
                lsum[r] += __expf(acc[r] * 0.03125f);
        }
        __syncthreads();
    }
    {                                              // jt == ib: masked tile
        STAGEQ(ib);
        __syncthreads();
        #pragma unroll
        for (int nt = 0; nt < 4; ++nt) {
            QK_TILE(acc, nt);
            const int gj = ib * 64 + nt * 16 + lr;
            #pragma unroll
            for (int r = 0; r < 4; ++r) {
                float e = __expf(acc[r] * 0.03125f);
                lsum[r] += (gj <= gi_base + r) ? e : 0.f;
            }
        }
        __syncthreads();
    }
    float linv[4];
    #pragma unroll
    for (int r = 0; r < 4; ++r) {
        float v = lsum[r];
        v += __shfl_xor(v, 1);
        v += __shfl_xor(v, 2);
        v += __shfl_xor(v, 4);
        v += __shfl_xor(v, 8);
        linv[r] = 1.0f / v;
    }
    // ---------------- PASS B: normalized writes via LDS transpose ------------
    for (int jt = 0; jt <= ib; ++jt) {
        STAGEQ(jt);
        __syncthreads();
        if (jt < ib) {                             // unmasked
            #pragma unroll
            for (int nt = 0; nt < 4; ++nt) {
                QK_TILE(acc, nt);
                #pragma unroll
                for (int r = 0; r < 4; ++r)
                    eT[wid * 16 + 4 * lg + r][nt * 16 + lr] =
                        __expf(acc[r] * 0.03125f) * linv[r];
            }
        } else {                                   // jt == ib: masked + diag
            #pragma unroll
            for (int nt = 0; nt < 4; ++nt) {
                QK_TILE(acc, nt);
                const int gj = ib * 64 + nt * 16 + lr;
                #pragma unroll
                for (int r = 0; r < 4; ++r) {
                    const int gi = gi_base + r;
                    float e = __expf(acc[r] * 0.03125f) * linv[r];
                    e = (gj <= gi) ? e : 0.f;
                    eT[wid * 16 + 4 * lg + r][nt * 16 + lr] = e;
                    if (gj == gi) diag[(size_t)bh * NT + gi] = e;
                }
            }
        }
        __syncthreads();   // eT complete; smQ consumed
        #pragma unroll
        for (int it = 0; it < 4; ++it) {
            const int chunk = it * 256 + tid;
            const int row = chunk >> 4, c4 = chunk & 15;
            const f32x4 v4 = *(const f32x4*)&eT[row][c4 * 4];
            __builtin_nontemporal_store(
                v4, (f32x4*)&wbase[(size_t)(i0 + row) * NT + jt * 64 + c4 * 4]);
        }
        // next STAGEQ writes smQ (not eT); next eT write is after the next
        // __syncthreads, which orders this tile's eT reads before it.
    }
    #undef STAGEQ
    #undef QK_TILE
    // zero-fill row tails (1 KB bursts: 64 lanes x 16 B contiguous)
    const f32x4 z4 = {0.f, 0.f, 0.f, 0.f};
    const int tail0 = (ib + 1) * 64;
    const int ntail4 = (NT - tail0) >> 2;          // f32x4 chunks per row
    #pragma unroll 4
    for (int rr = 0; rr < 16; ++rr) {
        const int row = i0 + wid * 16 + rr;
        f32x4* tb = (f32x4*)&wbase[(size_t)row * NT + tail0];
        for (int c = l; c < ntail4; c += 64)
            __builtin_nontemporal_store(z4, tb + c);
    }
}

// ---- K3: out = (diag*v concat) @ Wp^T + bp; A reg-staged fused scale --------
__global__ __launch_bounds__(256) void out_gemm(
    const ushort_t* __restrict__ vs, const float* __restrict__ diag,
    const ushort_t* __restrict__ Wpb, const float* __restrict__ bpv,
    float* __restrict__ out)
{
    __shared__ ushort_t smA[128 * 64];   // 16 KB
    __shared__ ushort_t smB[128 * 64];   // 16 KB
    const int n0 = blockIdx.x * 128;
    const int m0 = blockIdx.y * 128;
    const int tid = threadIdx.x;
    const int wid = tid >> 6, l = tid & 63, lr = l & 15, lg = l >> 4;
    const int wr = wid >> 1, wc = wid & 1;

    const int srow = wid * 32 + (l >> 3);            // + j*8; srow&7 == l>>3
    const int scol0 = ((l & 7) ^ (srow & 7)) * 8;    // swizzled col (elems)

    f32x4 acc[4][4];
    #pragma unroll
    for (int i = 0; i < 4; ++i)
        #pragma unroll
        for (int j = 0; j < 4; ++j) acc[i][j] = (f32x4){0.f, 0.f, 0.f, 0.f};

    for (int k0 = 0; k0 < NC; k0 += 64) {
        const int h = k0 >> 6;
        #pragma unroll
        for (int j = 0; j < 4; ++j) {
            GLD_LDS16(Wpb + (size_t)(n0 + srow + j * 8) * NC + k0 + scol0,
                      &smB[wid * 2048 + j * 512]);
        }
        #pragma unroll
        for (int j = 0; j < 4; ++j) {
            const int row = srow + j * 8;
            const int m = m0 + row, bb = m >> 11, tt = m & 2047;
            const size_t bhT = (size_t)(bb * NH + h) * NT + tt;
            const short8 u = *(const short8*)(vs + bhT * NHD + (l & 7) * 8);
            const float dg = diag[bhT];
            short8 sc;
            #pragma unroll
            for (int e = 0; e < 8; ++e)
                sc[e] = (short)f2bf(bf2f((ushort_t)u[e]) * dg);
            *(short8*)&smA[row * 64 + scol0] = sc;
        }
        __syncthreads();
        short8 a[4][2], b[4][2];
        #pragma unroll
        for (int mi = 0; mi < 4; ++mi) {
            const int rowA = 64 * wr + 16 * mi + lr;
            const int sw = (rowA & 7) * 8;
            a[mi][0] = *(const short8*)&smA[rowA * 64 + ((8 * lg) ^ sw)];
            a[mi][1] = *(const short8*)&smA[rowA * 64 + ((32 + 8 * lg) ^ sw)];
        }
        #pragma unroll
        for (int ni = 0; ni < 4; ++ni) {
            const int rowB = 64 * wc + 16 * ni + lr;
            const int sw = (rowB & 7) * 8;
            b[ni][0] = *(const short8*)&smB[rowB * 64 + ((8 * lg) ^ sw)];
            b[ni][1] = *(const short8*)&smB[rowB * 64 + ((32 + 8 * lg) ^ sw)];
        }
        #pragma unroll
        for (int mi = 0; mi < 4; ++mi)
            #pragma unroll
            for (int ni = 0; ni < 4; ++ni) {
                acc[mi][ni] = __builtin_amdgcn_mfma_f32_16x16x32_bf16(
                    a[mi][0], b[ni][0], acc[mi][ni], 0, 0, 0);
                acc[mi][ni] = __builtin_amdgcn_mfma_f32_16x16x32_bf16(
                    a[mi][1], b[ni][1], acc[mi][ni], 0, 0, 0);
            }
        __syncthreads();
    }
    float bias[4];
    #pragma unroll
    for (int ni = 0; ni < 4; ++ni) bias[ni] = bpv[n0 + 64 * wc + 16 * ni + lr];
    #pragma unroll
    for (int mi = 0; mi < 4; ++mi) {
        #pragma unroll
        for (int r = 0; r < 4; ++r) {
            const int m = m0 + 64 * wr + 16 * mi + 4 * lg + r;
            float* orow = out + (size_t)m * NC + n0 + 64 * wc;
            #pragma unroll
            for (int ni = 0; ni < 4; ++ni)
                __builtin_nontemporal_store(acc[mi][ni][r] + bias[ni],
                                            &orow[16 * ni + lr]);
        }
    }
}

extern "C" void kernel_launch(void* const* d_in, const int* in_sizes, int n_in,
                              void* d_out, int out_size, void* d_ws, size_t ws_size,
                              hipStream_t stream)
{
    const float* x  = (const float*)d_in[0];
    const float* Wq = (const float*)d_in[1];
    const float* Wk = (const float*)d_in[2];
    const float* Wv = (const float*)d_in[3];
    const float* Wp = (const float*)d_in[4];
    const float* bp = (const float*)d_in[5];

    float* out = (float*)d_out;                      // f32 outputs
    float* w = out + (size_t)NB * NT * NC;           // weights region (f32)

    ushort_t* xbf = (ushort_t*)d_ws;                             // 16.8 MB
    ushort_t* Wt  = xbf + (size_t)NB * NT * NC;                  // 6.3 MB
    ushort_t* qs  = Wt + (size_t)3 * NH * NHD * NC;              // 3 x 16.8 MB
    ushort_t* ks  = qs + (size_t)BH * NT * NHD;
    ushort_t* vs  = ks + (size_t)BH * NT * NHD;
    float* diag   = (float*)(vs + (size_t)BH * NT * NHD);        // 0.5 MB
    ushort_t* Wpb = (ushort_t*)(diag + (size_t)BH * NT);         // 2 MB

    cvt_all<<<21504, 256, 0, stream>>>(x, Wq, Wk, Wv, Wp, xbf, Wpb, Wt);
    qkv_gemm2<<<1536, 256, 0, stream>>>(xbf, Wt, qs, ks, vs);
    scores_mfma<<<dim3(NT / 64, BH), 256, 0, stream>>>(qs, ks, w, diag);
    out_gemm<<<dim3(8, 64), 256, 0, stream>>>(vs, diag, Wpb, bp, out);
}